// Round 4
// baseline (757.841 us; speedup 1.0000x reference)
//
#include <hip/hip_runtime.h>

#define FLTMAX 3.402823466e+38f

// ---------------------------------------------------------------------------
// Geometry:
//   Layer1: B=1024, N=784, Np=896, S=7, F=512, I=8, K=4
//   Layer2: B=1024, N=512, Np=512, S=4, F=10,  I=8, K=4
// P1 plane (s,i,k): [1024 x 512]; P2 plane: [1024 x 10]
// ---------------------------------------------------------------------------

__global__ void init_kernel(float* __restrict__ acc1, unsigned* __restrict__ stats1)
{
    int gid = blockIdx.x * 256 + threadIdx.x;
    if (gid < 1024 * 512) acc1[gid] = 0.f;
    if (gid < 224) { stats1[gid * 2] = 0x7F7FFFFFu; stats1[gid * 2 + 1] = 0u; }
}

// xq1[b][n] = rint(clip(x,0,1)*255), padded to 896 with 0; sx1[b] = row sum
__global__ void prep1_kernel(const float* __restrict__ x, float* __restrict__ xq1,
                             float* __restrict__ sx1)
{
    __shared__ float red[128];
    int b = blockIdx.x;
    float psum = 0.f;
    for (int n = threadIdx.x; n < 896; n += 128) {
        float v = 0.f;
        if (n < 784) {
            float xv = x[b * 784 + n];
            xv = fminf(fmaxf(xv, 0.f), 1.f);
            v = rintf(__fmul_rn(xv, 255.f));
        }
        xq1[b * 896 + n] = v;
        psum += v;  // integer-valued, exact in any order
    }
    red[threadIdx.x] = psum;
    __syncthreads();
    for (int w = 64; w >= 1; w >>= 1) {
        if (threadIdx.x < w) red[threadIdx.x] += red[threadIdx.x + w];
        __syncthreads();
    }
    if (threadIdx.x == 0) sx1[b] = red[0];
}

// Pack xq1 bits: xqb[i][b][w] = 32 n-bits (n = w*32..w*32+31) of bit-plane i.
__global__ void bitpack_kernel(const float* __restrict__ xq1, unsigned* __restrict__ xqb)
{
    int gid = blockIdx.x * 256 + threadIdx.x;   // 1024*28
    if (gid >= 1024 * 28) return;
    int b = gid / 28, w = gid % 28;
    unsigned words[8] = {0, 0, 0, 0, 0, 0, 0, 0};
    const float* src = &xq1[b * 896 + w * 32];
#pragma unroll 8
    for (int n = 0; n < 32; ++n) {
        int v = (int)src[n];
#pragma unroll
        for (int i = 0; i < 8; ++i) words[i] |= ((unsigned)((v >> i) & 1)) << n;
    }
#pragma unroll
    for (int i = 0; i < 8; ++i) xqb[(i * 1024 + b) * 28 + w] = words[i];
}

// Fused conductance-prep + transpose: writes g1t[n][k*512+f] directly.
// g = (slc*0.9+0.3)*(1+0.05*noise); rows n >= 784 are zero padding.
__global__ void prepg1t_kernel(const float* __restrict__ w1, const float* __restrict__ noise1,
                               float* __restrict__ g1t)
{
    __shared__ float t[4][32][33];
    const int n0 = blockIdx.x * 32, f0 = blockIdx.y * 32;
    const int tid = threadIdx.x;
    {
        int n = tid & 31, fi = tid >> 5;
#pragma unroll
        for (int p = 0; p < 4; ++p) {
            int f = p * 8 + fi;
            int gn = n0 + n, gf = f0 + f;
            float gv[4] = {0.f, 0.f, 0.f, 0.f};
            if (gn < 784) {
                float w = w1[gf * 784 + gn];
                float Xi = fminf(fmaxf(rintf(__fmul_rn(__fmul_rn(__fadd_rn(w, 1.f), 0.5f), 255.f)),
                                       0.f), 255.f);
                int xi = (int)Xi;
                float4 nz = *(const float4*)&noise1[(gf * 896 + gn) * 4];
                float nzv[4] = {nz.x, nz.y, nz.z, nz.w};
#pragma unroll
                for (int k = 0; k < 4; ++k) {
                    int slc = (xi >> (2 * k)) & 3;
                    float base = __fadd_rn(__fmul_rn((float)slc, 0.9f), 0.3f);
                    float nf = __fadd_rn(1.f, __fmul_rn(0.05f, nzv[k]));
                    gv[k] = __fmul_rn(base, nf);
                }
            }
#pragma unroll
            for (int k = 0; k < 4; ++k) t[k][n][f] = gv[k];
        }
    }
    __syncthreads();
    {
        int f = tid & 31, nn = tid >> 5;
#pragma unroll
        for (int p = 0; p < 4; ++p) {
            int n = p * 8 + nn;
#pragma unroll
            for (int k = 0; k < 4; ++k)
                g1t[(n0 + n) * 2048 + k * 512 + f0 + f] = t[k][n][f];
        }
    }
}

// g2t[n][k][f] layout for layer-2 matmul
__global__ void prepg2_kernel(const float* __restrict__ w3, const float* __restrict__ noise3,
                              float* __restrict__ g2t)
{
    int gid = blockIdx.x * 256 + threadIdx.x;
    if (gid >= 10 * 512) return;
    int f = gid / 512, n = gid % 512;
    float w = w3[f * 512 + n];
    float Xi = fminf(fmaxf(rintf(__fmul_rn(__fmul_rn(__fadd_rn(w, 1.f), 0.5f), 255.f)),
                           0.f), 255.f);
    int xi = (int)Xi;
#pragma unroll
    for (int k = 0; k < 4; ++k) {
        int slc = (xi >> (2 * k)) & 3;
        float base = __fadd_rn(__fmul_rn((float)slc, 0.9f), 0.3f);
        float nf = __fadd_rn(1.f, __fmul_rn(0.05f, noise3[(f * 512 + n) * 4 + k]));
        g2t[n * 40 + k * 10 + f] = __fmul_rn(base, nf);
    }
}

// Dummy-column path: one workgroup per (i,s) plane; Dq[(i*S+s)*1024 + b]
__global__ void dq_kernel(const float* __restrict__ xq, float* __restrict__ Dq,
                          int S, int rowstride)
{
    __shared__ float red[512];
    const int i = blockIdx.x / S, s = blockIdx.x % S;
    const int tid = threadIdx.x;
    float D[4];
    float mn = FLTMAX, mx = -FLTMAX;
#pragma unroll
    for (int u = 0; u < 4; ++u) {
        int b = tid + u * 256;
        const float4* row = (const float4*)&xq[b * rowstride + s * 128];
        int c = 0;
#pragma unroll 8
        for (int q = 0; q < 32; ++q) {
            float4 v = row[q];
            c += (((int)v.x >> i) & 1) + (((int)v.y >> i) & 1) +
                 (((int)v.z >> i) & 1) + (((int)v.w >> i) & 1);
        }
        D[u] = __fmul_rn((float)c, 0.3f);
        mn = fminf(mn, D[u]);
        mx = fmaxf(mx, D[u]);
    }
    red[tid] = mn; red[256 + tid] = mx;
    __syncthreads();
    for (int w = 128; w >= 1; w >>= 1) {
        if (tid < w) {
            red[tid] = fminf(red[tid], red[tid + w]);
            red[256 + tid] = fmaxf(red[256 + tid], red[256 + tid + w]);
        }
        __syncthreads();
    }
    mn = red[0]; mx = red[256];
    float step = __fmul_rn(__fsub_rn(mx, mn), 0.03125f);
    if (step <= 0.f) step = 1.f;
#pragma unroll
    for (int u = 0; u < 4; ++u) {
        int b = tid + u * 256;
        float idx = fminf(fmaxf(floorf(__fdiv_rn(__fsub_rn(D[u], mn), step)), 0.f), 31.f);
        Dq[(i * S + s) * 1024 + b] = __fadd_rn(__fmul_rn(idx, step), mn);
    }
}

// dterm[b] = sum_{i,s} Dq[i,s,b] * (85 * 2^i)
__global__ void dterm_kernel(const float* __restrict__ Dq, float* __restrict__ dterm, int S)
{
    int b = blockIdx.x * 256 + threadIdx.x;
    if (b >= 1024) return;
    float sum = 0.f;
    for (int i = 0; i < 8; ++i) {
        float sc = (float)(85 << i);
        for (int s = 0; s < S; ++s) sum = fmaf(Dq[(i * S + s) * 1024 + b], sc, sum);
    }
    dterm[b] = sum;
}

// ---------------------------------------------------------------------------
// Layer-1 GEMM: 128x128 tile, BK=32, 8x8 acc/thread, 256 threads.
// A comes from bit-packed words (registers), only B lives in LDS.
// Per a-step per wave: 2 ds_read_b128 + 8 bfe/cvt + 64 fma -> VALU-bound ~80%.
// Per-element chain: fmaf over n ascending (bit-exact vs R1/R2).
// ---------------------------------------------------------------------------
#define BK 32
__global__ __launch_bounds__(256, 4) void mm1_kernel(
    const unsigned* __restrict__ xqb, const float* __restrict__ g1t,
    float* __restrict__ P, unsigned* __restrict__ stats, int s, int i0)
{
    __shared__ __align__(16) float Bs[BK][132];
    __shared__ unsigned Abits[128];
    __shared__ float red[512];
    const int tid = threadIdx.x;
    const int il = blockIdx.x >> 3;             // chunk-local i
    const int i = i0 + il;
    const int b0 = (blockIdx.x & 7) * 128;
    const int colBase = blockIdx.y * 128;       // [0, 2048)
    const int tx = tid & 15, ty = tid >> 4;

    const int aB = tid >> 5;          // 0..7  (B rows: u*8 + aB)
    const int eB = (tid & 31) << 2;   // 0..124

    // prefetch chunk 0
    float4 pB[4];
    unsigned pAw = 0;
#pragma unroll
    for (int u = 0; u < 4; ++u)
        pB[u] = *(const float4*)&g1t[(s * 128 + u * 8 + aB) * 2048 + colBase + eB];
    if (tid < 128) pAw = xqb[(i * 1024 + b0 + tid) * 28 + s * 4];

    float acc[8][8] = {};

    for (int ac = 0; ac < 4; ++ac) {
        __syncthreads();
#pragma unroll
        for (int u = 0; u < 4; ++u)
            *(float4*)&Bs[u * 8 + aB][eB] = pB[u];
        if (tid < 128) Abits[tid] = pAw;
        __syncthreads();

        if (ac < 3) {
            const int n0 = s * 128 + (ac + 1) * BK;
#pragma unroll
            for (int u = 0; u < 4; ++u)
                pB[u] = *(const float4*)&g1t[(n0 + u * 8 + aB) * 2048 + colBase + eB];
            if (tid < 128) pAw = xqb[(i * 1024 + b0 + tid) * 28 + s * 4 + ac + 1];
        }

        unsigned wrd[8];
#pragma unroll
        for (int u = 0; u < 4; ++u) {
            wrd[u]     = Abits[(ty << 2) + u];
            wrd[4 + u] = Abits[64 + (ty << 2) + u];
        }

#pragma unroll 4
        for (int a = 0; a < BK; ++a) {
            float br[8];
            *(float4*)&br[0] = *(const float4*)&Bs[a][(tx << 2)];
            *(float4*)&br[4] = *(const float4*)&Bs[a][64 + (tx << 2)];
#pragma unroll
            for (int u = 0; u < 8; ++u) {
                float ab = (float)((wrd[u] >> a) & 1u);
#pragma unroll
                for (int v = 0; v < 8; ++v)
                    acc[u][v] = fmaf(ab, br[v], acc[u][v]);
            }
        }
    }

    // store P: rows il*1024 + b0 + uh*64 + ty*4 + u, cols colBase + vh*64 + tx*4
#pragma unroll
    for (int uh = 0; uh < 2; ++uh)
#pragma unroll
        for (int u = 0; u < 4; ++u) {
            int row = il * 1024 + b0 + uh * 64 + (ty << 2) + u;
#pragma unroll
            for (int vh = 0; vh < 2; ++vh) {
                float4 v = make_float4(acc[uh * 4 + u][vh * 4 + 0], acc[uh * 4 + u][vh * 4 + 1],
                                       acc[uh * 4 + u][vh * 4 + 2], acc[uh * 4 + u][vh * 4 + 3]);
                *(float4*)&P[(size_t)row * 2048 + colBase + vh * 64 + (tx << 2)] = v;
            }
        }

    float mn = acc[0][0], mx = acc[0][0];
#pragma unroll
    for (int u = 0; u < 8; ++u)
#pragma unroll
        for (int v = 0; v < 8; ++v) { mn = fminf(mn, acc[u][v]); mx = fmaxf(mx, acc[u][v]); }
    red[tid] = mn; red[256 + tid] = mx;
    __syncthreads();
    for (int w = 128; w >= 1; w >>= 1) {
        if (tid < w) {
            red[tid] = fminf(red[tid], red[tid + w]);
            red[256 + tid] = fmaxf(red[256 + tid], red[256 + tid + w]);
        }
        __syncthreads();
    }
    if (tid == 0) {
        int k = colBase >> 9;
        int slot = ((s * 8 + i) * 4 + k) * 2;
        atomicMin(&stats[slot], __float_as_uint(red[0]));      // P >= 0: uint order == float order
        atomicMax(&stats[slot + 1], __float_as_uint(red[256]));
    }
}

// ADC-quantize chunk planes and accumulate sum_{i,k} Pq*scal into acc1[b][f]
// float4 across f; per-component chain identical to scalar version.
__global__ void quant1_kernel(const float* __restrict__ P, const unsigned* __restrict__ stats,
                              float* __restrict__ acc1, int s, int i0, int ni)
{
    int gid = blockIdx.x * 256 + threadIdx.x;  // 131072
    int b = gid >> 7, f4 = gid & 127;
    float4 sum = make_float4(0.f, 0.f, 0.f, 0.f);
    for (int il = 0; il < ni; ++il) {
        int i = i0 + il;
#pragma unroll
        for (int k = 0; k < 4; ++k) {
            int slot = ((s * 8 + i) * 4 + k) * 2;
            float mn = __uint_as_float(stats[slot]);
            float mx = __uint_as_float(stats[slot + 1]);
            float step = __fmul_rn(__fsub_rn(mx, mn), 0.03125f);
            if (step <= 0.f) step = 1.f;
            float4 val = *(const float4*)&P[(size_t)(il * 1024 + b) * 2048 + (k << 9) + (f4 << 2)];
            float sc = (float)(1 << (i + 2 * k));
            float ix, pq;
            ix = fminf(fmaxf(floorf(__fdiv_rn(__fsub_rn(val.x, mn), step)), 0.f), 31.f);
            pq = __fadd_rn(__fmul_rn(ix, step), mn); sum.x = fmaf(pq, sc, sum.x);
            ix = fminf(fmaxf(floorf(__fdiv_rn(__fsub_rn(val.y, mn), step)), 0.f), 31.f);
            pq = __fadd_rn(__fmul_rn(ix, step), mn); sum.y = fmaf(pq, sc, sum.y);
            ix = fminf(fmaxf(floorf(__fdiv_rn(__fsub_rn(val.z, mn), step)), 0.f), 31.f);
            pq = __fadd_rn(__fmul_rn(ix, step), mn); sum.z = fmaf(pq, sc, sum.z);
            ix = fminf(fmaxf(floorf(__fdiv_rn(__fsub_rn(val.w, mn), step)), 0.f), 31.f);
            pq = __fadd_rn(__fmul_rn(ix, step), mn); sum.w = fmaf(pq, sc, sum.w);
        }
    }
    float4* ap = (float4*)&acc1[(b << 9) + (f4 << 2)];
    float4 a = *ap;
    a.x += sum.x; a.y += sum.y; a.z += sum.z; a.w += sum.w;
    *ap = a;
}

// out1 -> tanh -> xq2 (layer-2 quantized input codes)
__global__ void finish1_kernel(const float* __restrict__ acc1, const float* __restrict__ dterm1,
                               const float* __restrict__ sx1, float* __restrict__ xq2)
{
    int gid = blockIdx.x * 256 + threadIdx.x;  // 524288
    int b = gid >> 9;
    float total = __fsub_rn(acc1[gid], dterm1[b]);
    float acc = __fdiv_rn(total, 0.9f);
    float o = __fsub_rn(__fdiv_rn(__fmul_rn(2.f, acc), 65025.f), __fdiv_rn(sx1[b], 255.f));
    float h = tanhf(o);
    h = fminf(fmaxf(h, 0.f), 1.f);
    xq2[gid] = rintf(__fmul_rn(h, 255.f));
}

__global__ void sx2_kernel(const float* __restrict__ xq2, float* __restrict__ sx2)
{
    __shared__ float red[128];
    int b = blockIdx.x;
    float psum = 0.f;
    for (int n = threadIdx.x; n < 512; n += 128) psum += xq2[b * 512 + n];
    red[threadIdx.x] = psum;
    __syncthreads();
    for (int w = 64; w >= 1; w >>= 1) {
        if (threadIdx.x < w) red[threadIdx.x] += red[threadIdx.x + w];
        __syncthreads();
    }
    if (threadIdx.x == 0) sx2[b] = red[0];
}

// Layer-2 matmul: thread per (s,b,f), 32 accumulators (i,k)
__global__ void mm2_kernel(const float* __restrict__ xq2, const float* __restrict__ g2t,
                           float* __restrict__ P2)
{
    int gid = blockIdx.x * 256 + threadIdx.x;  // 40960
    if (gid >= 40960) return;
    int f = gid % 10;
    int b = (gid / 10) & 1023;
    int s = gid / 10240;
    float acc[8][4] = {};
    for (int a = 0; a < 128; ++a) {
        int n = s * 128 + a;
        int xi = (int)xq2[b * 512 + n];
        float g0 = g2t[n * 40 + f];
        float gA = g2t[n * 40 + 10 + f];
        float gB = g2t[n * 40 + 20 + f];
        float gC = g2t[n * 40 + 30 + f];
#pragma unroll
        for (int i = 0; i < 8; ++i) {
            float bi = (float)((xi >> i) & 1);
            acc[i][0] = fmaf(bi, g0, acc[i][0]);
            acc[i][1] = fmaf(bi, gA, acc[i][1]);
            acc[i][2] = fmaf(bi, gB, acc[i][2]);
            acc[i][3] = fmaf(bi, gC, acc[i][3]);
        }
    }
#pragma unroll
    for (int i = 0; i < 8; ++i)
#pragma unroll
        for (int k = 0; k < 4; ++k)
            P2[(size_t)((s * 8 + i) * 4 + k) * 10240 + b * 10 + f] = acc[i][k];
}

__global__ void stat2_kernel(const float* __restrict__ P2, float2* __restrict__ stats2)
{
    __shared__ float red[512];
    int p = blockIdx.x;  // 128 planes
    int tid = threadIdx.x;
    float mn = FLTMAX, mx = -FLTMAX;
    for (int t = tid; t < 10240; t += 256) {
        float v = P2[(size_t)p * 10240 + t];
        mn = fminf(mn, v); mx = fmaxf(mx, v);
    }
    red[tid] = mn; red[256 + tid] = mx;
    __syncthreads();
    for (int w = 128; w >= 1; w >>= 1) {
        if (tid < w) {
            red[tid] = fminf(red[tid], red[tid + w]);
            red[256 + tid] = fmaxf(red[256 + tid], red[256 + tid + w]);
        }
        __syncthreads();
    }
    if (tid == 0) {
        float step = __fmul_rn(__fsub_rn(red[256], red[0]), 0.03125f);
        if (step <= 0.f) step = 1.f;
        stats2[p] = make_float2(red[0], step);
    }
}

__global__ void out2_kernel(const float* __restrict__ P2, const float2* __restrict__ stats2,
                            const float* __restrict__ dterm2, const float* __restrict__ sx2,
                            float* __restrict__ out)
{
    int gid = blockIdx.x * 256 + threadIdx.x;  // 10240
    if (gid >= 10240) return;
    int b = gid / 10;
    float sum = 0.f;
    for (int s = 0; s < 4; ++s)
        for (int i = 0; i < 8; ++i)
#pragma unroll
            for (int k = 0; k < 4; ++k) {
                int p = (s * 8 + i) * 4 + k;
                float2 st = stats2[p];
                float val = P2[(size_t)p * 10240 + gid];
                float idx = fminf(fmaxf(floorf(__fdiv_rn(__fsub_rn(val, st.x), st.y)), 0.f), 31.f);
                float pq = __fadd_rn(__fmul_rn(idx, st.y), st.x);
                sum = fmaf(pq, (float)(1 << (i + 2 * k)), sum);
            }
    float total = __fsub_rn(sum, dterm2[b]);
    float acc = __fdiv_rn(total, 0.9f);
    out[gid] = __fsub_rn(__fdiv_rn(__fmul_rn(2.f, acc), 65025.f), __fdiv_rn(sx2[b], 255.f));
}

extern "C" void kernel_launch(void* const* d_in, const int* in_sizes, int n_in,
                              void* d_out, int out_size, void* d_ws, size_t ws_size,
                              hipStream_t stream)
{
    const float* x      = (const float*)d_in[0];
    const float* w1     = (const float*)d_in[1];
    const float* w3     = (const float*)d_in[2];
    const float* noise1 = (const float*)d_in[3];
    const float* noise3 = (const float*)d_in[4];
    float* out = (float*)d_out;
    float* ws  = (float*)d_ws;

    // ws layout (float offsets)
    float*    xq1    = ws + 0;         // 1024*896
    float*    g1t    = ws + 917504;    // 896*2048
    float*    acc1   = ws + 2752512;   // 1024*512
    float*    xq2    = ws + 3276800;   // 1024*512
    float*    P2     = ws + 3801088;   // 128*10240
    float*    g2t    = ws + 5111808;   // 512*40
    float*    Dq1    = ws + 5132288;   // 56*1024
    float*    Dq2    = ws + 5189632;   // 32*1024
    float*    sx1    = ws + 5222400;   // 1024
    float*    sx2    = ws + 5223424;   // 1024
    float*    dterm1 = ws + 5224448;   // 1024
    float*    dterm2 = ws + 5225472;   // 1024
    float2*   stats2 = (float2*)(ws + 5226496);   // 128 pairs
    unsigned* stats1 = (unsigned*)(ws + 5226752); // 224*2 (pad to 512)
    unsigned* xqb    = (unsigned*)(ws + 5227264); // 8*1024*28 words
    float*    Ps     = ws + 5456640;   // ni * 1024 * 2048

    const size_t fixedf = 5456640;
    int ni = 8;  // i-planes per P chunk; shrink to fit ws
    while (ni > 1 && (fixedf + (size_t)ni * 2097152) * sizeof(float) > ws_size) ni >>= 1;

    init_kernel<<<2048, 256, 0, stream>>>(acc1, stats1);
    prep1_kernel<<<1024, 128, 0, stream>>>(x, xq1, sx1);
    prepg1t_kernel<<<dim3(28, 16), 256, 0, stream>>>(w1, noise1, g1t);
    bitpack_kernel<<<112, 256, 0, stream>>>(xq1, xqb);
    dq_kernel<<<56, 256, 0, stream>>>(xq1, Dq1, 7, 896);
    dterm_kernel<<<4, 256, 0, stream>>>(Dq1, dterm1, 7);

    for (int s = 0; s < 7; ++s)
        for (int i0 = 0; i0 < 8; i0 += ni) {
            mm1_kernel<<<dim3(8 * ni, 16), 256, 0, stream>>>(xqb, g1t, Ps, stats1, s, i0);
            quant1_kernel<<<512, 256, 0, stream>>>(Ps, stats1, acc1, s, i0, ni);
        }

    finish1_kernel<<<2048, 256, 0, stream>>>(acc1, dterm1, sx1, xq2);
    sx2_kernel<<<1024, 128, 0, stream>>>(xq2, sx2);
    prepg2_kernel<<<20, 256, 0, stream>>>(w3, noise3, g2t);
    dq_kernel<<<32, 256, 0, stream>>>(xq2, Dq2, 4, 512);
    dterm_kernel<<<4, 256, 0, stream>>>(Dq2, dterm2, 4);
    mm2_kernel<<<160, 256, 0, stream>>>(xq2, g2t, P2);
    stat2_kernel<<<128, 256, 0, stream>>>(P2, stats2);
    out2_kernel<<<40, 256, 0, stream>>>(P2, stats2, dterm2, sx2, out);
}

// Round 5
// 668.094 us; speedup vs baseline: 1.1343x; 1.1343x over previous
//
#include <hip/hip_runtime.h>

#define FLTMAX 3.402823466e+38f

// ---------------------------------------------------------------------------
// Geometry:
//   Layer1: B=1024, N=784, Np=896, S=7, F=512, I=8, K=4
//   Layer2: B=1024, N=512, Np=512, S=4, F=10,  I=8, K=4
// P1 plane (s,i,k): [1024 x 512]; P2 plane: [1024 x 10]
// ---------------------------------------------------------------------------

// xq1[b][n] = rint(clip(x,0,1)*255), padded to 896 with 0; sx1[b] = row sum.
// Also initializes stats1 (consumed only after this dispatch completes).
__global__ void prep1_kernel(const float* __restrict__ x, float* __restrict__ xq1,
                             float* __restrict__ sx1, unsigned* __restrict__ stats1)
{
    __shared__ float red[128];
    int b = blockIdx.x;
    if (blockIdx.x == 0) {
        for (int t = threadIdx.x; t < 224; t += 128) {
            stats1[t * 2] = 0x7F7FFFFFu; stats1[t * 2 + 1] = 0u;
        }
    }
    float psum = 0.f;
    for (int n = threadIdx.x; n < 896; n += 128) {
        float v = 0.f;
        if (n < 784) {
            float xv = x[b * 784 + n];
            xv = fminf(fmaxf(xv, 0.f), 1.f);
            v = rintf(__fmul_rn(xv, 255.f));
        }
        xq1[b * 896 + n] = v;
        psum += v;  // integer-valued, exact in any order
    }
    red[threadIdx.x] = psum;
    __syncthreads();
    for (int w = 64; w >= 1; w >>= 1) {
        if (threadIdx.x < w) red[threadIdx.x] += red[threadIdx.x + w];
        __syncthreads();
    }
    if (threadIdx.x == 0) sx1[b] = red[0];
}

// Pack xq1 bits: xqb[i][b][w] = 32 n-bits (n = w*32..w*32+31) of bit-plane i.
__global__ void bitpack_kernel(const float* __restrict__ xq1, unsigned* __restrict__ xqb)
{
    int gid = blockIdx.x * 256 + threadIdx.x;   // 1024*28
    if (gid >= 1024 * 28) return;
    int b = gid / 28, w = gid % 28;
    unsigned words[8] = {0, 0, 0, 0, 0, 0, 0, 0};
    const float* src = &xq1[b * 896 + w * 32];
#pragma unroll 8
    for (int n = 0; n < 32; ++n) {
        int v = (int)src[n];
#pragma unroll
        for (int i = 0; i < 8; ++i) words[i] |= ((unsigned)((v >> i) & 1)) << n;
    }
#pragma unroll
    for (int i = 0; i < 8; ++i) xqb[(i * 1024 + b) * 28 + w] = words[i];
}

// Fused conductance-prep + transpose: writes g1t[n][k*512+f] directly.
__global__ void prepg1t_kernel(const float* __restrict__ w1, const float* __restrict__ noise1,
                               float* __restrict__ g1t)
{
    __shared__ float t[4][32][33];
    const int n0 = blockIdx.x * 32, f0 = blockIdx.y * 32;
    const int tid = threadIdx.x;
    {
        int n = tid & 31, fi = tid >> 5;
#pragma unroll
        for (int p = 0; p < 4; ++p) {
            int f = p * 8 + fi;
            int gn = n0 + n, gf = f0 + f;
            float gv[4] = {0.f, 0.f, 0.f, 0.f};
            if (gn < 784) {
                float w = w1[gf * 784 + gn];
                float Xi = fminf(fmaxf(rintf(__fmul_rn(__fmul_rn(__fadd_rn(w, 1.f), 0.5f), 255.f)),
                                       0.f), 255.f);
                int xi = (int)Xi;
                float4 nz = *(const float4*)&noise1[(gf * 896 + gn) * 4];
                float nzv[4] = {nz.x, nz.y, nz.z, nz.w};
#pragma unroll
                for (int k = 0; k < 4; ++k) {
                    int slc = (xi >> (2 * k)) & 3;
                    float base = __fadd_rn(__fmul_rn((float)slc, 0.9f), 0.3f);
                    float nf = __fadd_rn(1.f, __fmul_rn(0.05f, nzv[k]));
                    gv[k] = __fmul_rn(base, nf);
                }
            }
#pragma unroll
            for (int k = 0; k < 4; ++k) t[k][n][f] = gv[k];
        }
    }
    __syncthreads();
    {
        int f = tid & 31, nn = tid >> 5;
#pragma unroll
        for (int p = 0; p < 4; ++p) {
            int n = p * 8 + nn;
#pragma unroll
            for (int k = 0; k < 4; ++k)
                g1t[(n0 + n) * 2048 + k * 512 + f0 + f] = t[k][n][f];
        }
    }
}

// g2t[n][k][f] layout for layer-2 matmul
__global__ void prepg2_kernel(const float* __restrict__ w3, const float* __restrict__ noise3,
                              float* __restrict__ g2t)
{
    int gid = blockIdx.x * 256 + threadIdx.x;
    if (gid >= 10 * 512) return;
    int f = gid / 512, n = gid % 512;
    float w = w3[f * 512 + n];
    float Xi = fminf(fmaxf(rintf(__fmul_rn(__fmul_rn(__fadd_rn(w, 1.f), 0.5f), 255.f)),
                           0.f), 255.f);
    int xi = (int)Xi;
#pragma unroll
    for (int k = 0; k < 4; ++k) {
        int slc = (xi >> (2 * k)) & 3;
        float base = __fadd_rn(__fmul_rn((float)slc, 0.9f), 0.3f);
        float nf = __fadd_rn(1.f, __fmul_rn(0.05f, noise3[(f * 512 + n) * 4 + k]));
        g2t[n * 40 + k * 10 + f] = __fmul_rn(base, nf);
    }
}

// Dummy-column via popcount of bit-packed words; one block per (i,s) plane.
// D = 0.3 * popcount(128 bits) — exactly matches the float-sum original.
__global__ void dqpop_kernel(const unsigned* __restrict__ xqb, float* __restrict__ Dq,
                             int S, int wpr)
{
    __shared__ float red[512];
    const int i = blockIdx.x / S, s = blockIdx.x % S;
    const int tid = threadIdx.x;
    float D[4];
    float mn = FLTMAX, mx = -FLTMAX;
#pragma unroll
    for (int u = 0; u < 4; ++u) {
        int b = tid + u * 256;
        uint4 w = *(const uint4*)&xqb[(i * 1024 + b) * wpr + s * 4];
        int c = __popc(w.x) + __popc(w.y) + __popc(w.z) + __popc(w.w);
        D[u] = __fmul_rn((float)c, 0.3f);
        mn = fminf(mn, D[u]);
        mx = fmaxf(mx, D[u]);
    }
    red[tid] = mn; red[256 + tid] = mx;
    __syncthreads();
    for (int w = 128; w >= 1; w >>= 1) {
        if (tid < w) {
            red[tid] = fminf(red[tid], red[tid + w]);
            red[256 + tid] = fmaxf(red[256 + tid], red[256 + tid + w]);
        }
        __syncthreads();
    }
    mn = red[0]; mx = red[256];
    float step = __fmul_rn(__fsub_rn(mx, mn), 0.03125f);
    if (step <= 0.f) step = 1.f;
#pragma unroll
    for (int u = 0; u < 4; ++u) {
        int b = tid + u * 256;
        float idx = fminf(fmaxf(floorf(__fdiv_rn(__fsub_rn(D[u], mn), step)), 0.f), 31.f);
        Dq[(i * S + s) * 1024 + b] = __fadd_rn(__fmul_rn(idx, step), mn);
    }
}

// dterm[b] = sum_{i,s} Dq[i,s,b] * (85 * 2^i)
__global__ void dterm_kernel(const float* __restrict__ Dq, float* __restrict__ dterm, int S)
{
    int b = blockIdx.x * 256 + threadIdx.x;
    if (b >= 1024) return;
    float sum = 0.f;
    for (int i = 0; i < 8; ++i) {
        float sc = (float)(85 << i);
        for (int s = 0; s < S; ++s) sum = fmaf(Dq[(i * S + s) * 1024 + b], sc, sum);
    }
    dterm[b] = sum;
}

// ---------------------------------------------------------------------------
// Layer-1 GEMM, s-grouped: grid.x = Gc*64 (sl, il, b-tile), grid.y = 16 (cols).
// 128x128 tile, BK=32, 8x8 acc/thread; A from bit-packed words, B in LDS.
// Per-element chain: fmaf over n ascending (bit-exact vs R1..R4).
// ---------------------------------------------------------------------------
#define BK 32
__global__ __launch_bounds__(256, 4) void mm1_kernel(
    const unsigned* __restrict__ xqb, const float* __restrict__ g1t,
    float* __restrict__ P, unsigned* __restrict__ stats, int s0)
{
    __shared__ __align__(16) float Bs[BK][132];
    __shared__ unsigned Abits[128];
    __shared__ float red[512];
    const int tid = threadIdx.x;
    const int sl = blockIdx.x >> 6;
    const int r = blockIdx.x & 63;
    const int i = r >> 3;                       // il == global i (all 8 per dispatch)
    const int b0 = (r & 7) * 128;
    const int s = s0 + sl;
    const int colBase = blockIdx.y * 128;       // [0, 2048)
    const int tx = tid & 15, ty = tid >> 4;

    const int aB = tid >> 5;          // 0..7  (B rows: u*8 + aB)
    const int eB = (tid & 31) << 2;   // 0..124

    // prefetch chunk 0
    float4 pB[4];
    unsigned pAw = 0;
#pragma unroll
    for (int u = 0; u < 4; ++u)
        pB[u] = *(const float4*)&g1t[(s * 128 + u * 8 + aB) * 2048 + colBase + eB];
    if (tid < 128) pAw = xqb[(i * 1024 + b0 + tid) * 28 + s * 4];

    float acc[8][8] = {};

    for (int ac = 0; ac < 4; ++ac) {
        __syncthreads();
#pragma unroll
        for (int u = 0; u < 4; ++u)
            *(float4*)&Bs[u * 8 + aB][eB] = pB[u];
        if (tid < 128) Abits[tid] = pAw;
        __syncthreads();

        if (ac < 3) {
            const int n0 = s * 128 + (ac + 1) * BK;
#pragma unroll
            for (int u = 0; u < 4; ++u)
                pB[u] = *(const float4*)&g1t[(n0 + u * 8 + aB) * 2048 + colBase + eB];
            if (tid < 128) pAw = xqb[(i * 1024 + b0 + tid) * 28 + s * 4 + ac + 1];
        }

        unsigned wrd[8];
#pragma unroll
        for (int u = 0; u < 4; ++u) {
            wrd[u]     = Abits[(ty << 2) + u];
            wrd[4 + u] = Abits[64 + (ty << 2) + u];
        }

#pragma unroll 4
        for (int a = 0; a < BK; ++a) {
            float br[8];
            *(float4*)&br[0] = *(const float4*)&Bs[a][(tx << 2)];
            *(float4*)&br[4] = *(const float4*)&Bs[a][64 + (tx << 2)];
#pragma unroll
            for (int u = 0; u < 8; ++u) {
                float ab = (float)((wrd[u] >> a) & 1u);
#pragma unroll
                for (int v = 0; v < 8; ++v)
                    acc[u][v] = fmaf(ab, br[v], acc[u][v]);
            }
        }
    }

    // store P: rows (sl*8+i)*1024 + b0 + uh*64 + ty*4 + u
#pragma unroll
    for (int uh = 0; uh < 2; ++uh)
#pragma unroll
        for (int u = 0; u < 4; ++u) {
            int row = (sl * 8 + i) * 1024 + b0 + uh * 64 + (ty << 2) + u;
#pragma unroll
            for (int vh = 0; vh < 2; ++vh) {
                float4 v = make_float4(acc[uh * 4 + u][vh * 4 + 0], acc[uh * 4 + u][vh * 4 + 1],
                                       acc[uh * 4 + u][vh * 4 + 2], acc[uh * 4 + u][vh * 4 + 3]);
                *(float4*)&P[(size_t)row * 2048 + colBase + vh * 64 + (tx << 2)] = v;
            }
        }

    float mn = acc[0][0], mx = acc[0][0];
#pragma unroll
    for (int u = 0; u < 8; ++u)
#pragma unroll
        for (int v = 0; v < 8; ++v) { mn = fminf(mn, acc[u][v]); mx = fmaxf(mx, acc[u][v]); }
    red[tid] = mn; red[256 + tid] = mx;
    __syncthreads();
    for (int w = 128; w >= 1; w >>= 1) {
        if (tid < w) {
            red[tid] = fminf(red[tid], red[tid + w]);
            red[256 + tid] = fmaxf(red[256 + tid], red[256 + tid + w]);
        }
        __syncthreads();
    }
    if (tid == 0) {
        int k = colBase >> 9;
        int slot = ((s * 8 + i) * 4 + k) * 2;
        atomicMin(&stats[slot], __float_as_uint(red[0]));      // P >= 0: uint order == float order
        atomicMax(&stats[slot + 1], __float_as_uint(red[256]));
    }
}

// ADC-quantize G s-planes and fold into acc1 with the exact original chain:
// for s ascending: acc1 += (i-outer, k-inner fmaf chain). first => acc1 = .
__global__ void quant1_kernel(const float* __restrict__ P, const unsigned* __restrict__ stats,
                              float* __restrict__ acc1, int s0, int G, int first)
{
    int gid = blockIdx.x * 256 + threadIdx.x;  // 131072
    int b = gid >> 7, f4 = gid & 127;
    float4 accR;
    if (first) accR = make_float4(0.f, 0.f, 0.f, 0.f);
    else       accR = *(const float4*)&acc1[(b << 9) + (f4 << 2)];
    for (int sl = 0; sl < G; ++sl) {
        int s = s0 + sl;
        float4 sum = make_float4(0.f, 0.f, 0.f, 0.f);
        for (int i = 0; i < 8; ++i) {
#pragma unroll
            for (int k = 0; k < 4; ++k) {
                int slot = ((s * 8 + i) * 4 + k) * 2;
                float mn = __uint_as_float(stats[slot]);
                float mx = __uint_as_float(stats[slot + 1]);
                float step = __fmul_rn(__fsub_rn(mx, mn), 0.03125f);
                if (step <= 0.f) step = 1.f;
                float4 val = *(const float4*)&P[(size_t)((sl * 8 + i) * 1024 + b) * 2048
                                                + (k << 9) + (f4 << 2)];
                float sc = (float)(1 << (i + 2 * k));
                float ix, pq;
                ix = fminf(fmaxf(floorf(__fdiv_rn(__fsub_rn(val.x, mn), step)), 0.f), 31.f);
                pq = __fadd_rn(__fmul_rn(ix, step), mn); sum.x = fmaf(pq, sc, sum.x);
                ix = fminf(fmaxf(floorf(__fdiv_rn(__fsub_rn(val.y, mn), step)), 0.f), 31.f);
                pq = __fadd_rn(__fmul_rn(ix, step), mn); sum.y = fmaf(pq, sc, sum.y);
                ix = fminf(fmaxf(floorf(__fdiv_rn(__fsub_rn(val.z, mn), step)), 0.f), 31.f);
                pq = __fadd_rn(__fmul_rn(ix, step), mn); sum.z = fmaf(pq, sc, sum.z);
                ix = fminf(fmaxf(floorf(__fdiv_rn(__fsub_rn(val.w, mn), step)), 0.f), 31.f);
                pq = __fadd_rn(__fmul_rn(ix, step), mn); sum.w = fmaf(pq, sc, sum.w);
            }
        }
        accR.x = __fadd_rn(accR.x, sum.x);
        accR.y = __fadd_rn(accR.y, sum.y);
        accR.z = __fadd_rn(accR.z, sum.z);
        accR.w = __fadd_rn(accR.w, sum.w);
    }
    *(float4*)&acc1[(b << 9) + (f4 << 2)] = accR;
}

// out1 -> tanh -> xq2 codes; also emit layer-2 bit-planes xqb2 via ballot.
__global__ void finish1_kernel(const float* __restrict__ acc1, const float* __restrict__ dterm1,
                               const float* __restrict__ sx1, float* __restrict__ xq2,
                               unsigned* __restrict__ xqb2)
{
    int gid = blockIdx.x * 256 + threadIdx.x;  // 524288
    int b = gid >> 9, f = gid & 511;
    float total = __fsub_rn(acc1[gid], dterm1[b]);
    float acc = __fdiv_rn(total, 0.9f);
    float o = __fsub_rn(__fdiv_rn(__fmul_rn(2.f, acc), 65025.f), __fdiv_rn(sx1[b], 255.f));
    float h = tanhf(o);
    h = fminf(fmaxf(h, 0.f), 1.f);
    float code = rintf(__fmul_rn(h, 255.f));
    xq2[gid] = code;
    int ci = (int)code;
    int lane = threadIdx.x & 63;
#pragma unroll
    for (int i = 0; i < 8; ++i) {
        unsigned long long m = __ballot((ci >> i) & 1);
        if ((lane & 31) == 0) {
            unsigned wv = (lane & 32) ? (unsigned)(m >> 32) : (unsigned)m;
            xqb2[(i * 1024 + b) * 16 + (f >> 5)] = wv;
        }
    }
}

__global__ void sx2_kernel(const float* __restrict__ xq2, float* __restrict__ sx2)
{
    __shared__ float red[128];
    int b = blockIdx.x;
    float psum = 0.f;
    for (int n = threadIdx.x; n < 512; n += 128) psum += xq2[b * 512 + n];
    red[threadIdx.x] = psum;
    __syncthreads();
    for (int w = 64; w >= 1; w >>= 1) {
        if (threadIdx.x < w) red[threadIdx.x] += red[threadIdx.x + w];
        __syncthreads();
    }
    if (threadIdx.x == 0) sx2[b] = red[0];
}

// Layer-2 matmul: thread per (s,b,f), 32 accumulators (i,k)
__global__ void mm2_kernel(const float* __restrict__ xq2, const float* __restrict__ g2t,
                           float* __restrict__ P2)
{
    int gid = blockIdx.x * 256 + threadIdx.x;  // 40960
    if (gid >= 40960) return;
    int f = gid % 10;
    int b = (gid / 10) & 1023;
    int s = gid / 10240;
    float acc[8][4] = {};
    for (int a = 0; a < 128; ++a) {
        int n = s * 128 + a;
        int xi = (int)xq2[b * 512 + n];
        float g0 = g2t[n * 40 + f];
        float gA = g2t[n * 40 + 10 + f];
        float gB = g2t[n * 40 + 20 + f];
        float gC = g2t[n * 40 + 30 + f];
#pragma unroll
        for (int i = 0; i < 8; ++i) {
            float bi = (float)((xi >> i) & 1);
            acc[i][0] = fmaf(bi, g0, acc[i][0]);
            acc[i][1] = fmaf(bi, gA, acc[i][1]);
            acc[i][2] = fmaf(bi, gB, acc[i][2]);
            acc[i][3] = fmaf(bi, gC, acc[i][3]);
        }
    }
#pragma unroll
    for (int i = 0; i < 8; ++i)
#pragma unroll
        for (int k = 0; k < 4; ++k)
            P2[(size_t)((s * 8 + i) * 4 + k) * 10240 + b * 10 + f] = acc[i][k];
}

__global__ void stat2_kernel(const float* __restrict__ P2, float2* __restrict__ stats2)
{
    __shared__ float red[512];
    int p = blockIdx.x;  // 128 planes
    int tid = threadIdx.x;
    float mn = FLTMAX, mx = -FLTMAX;
    for (int t = tid; t < 10240; t += 256) {
        float v = P2[(size_t)p * 10240 + t];
        mn = fminf(mn, v); mx = fmaxf(mx, v);
    }
    red[tid] = mn; red[256 + tid] = mx;
    __syncthreads();
    for (int w = 128; w >= 1; w >>= 1) {
        if (tid < w) {
            red[tid] = fminf(red[tid], red[tid + w]);
            red[256 + tid] = fmaxf(red[256 + tid], red[256 + tid + w]);
        }
        __syncthreads();
    }
    if (tid == 0) {
        float step = __fmul_rn(__fsub_rn(red[256], red[0]), 0.03125f);
        if (step <= 0.f) step = 1.f;
        stats2[p] = make_float2(red[0], step);
    }
}

__global__ void out2_kernel(const float* __restrict__ P2, const float2* __restrict__ stats2,
                            const float* __restrict__ dterm2, const float* __restrict__ sx2,
                            float* __restrict__ out)
{
    int gid = blockIdx.x * 256 + threadIdx.x;  // 10240
    if (gid >= 10240) return;
    int b = gid / 10;
    float sum = 0.f;
    for (int s = 0; s < 4; ++s)
        for (int i = 0; i < 8; ++i)
#pragma unroll
            for (int k = 0; k < 4; ++k) {
                int p = (s * 8 + i) * 4 + k;
                float2 st = stats2[p];
                float val = P2[(size_t)p * 10240 + gid];
                float idx = fminf(fmaxf(floorf(__fdiv_rn(__fsub_rn(val, st.x), st.y)), 0.f), 31.f);
                float pq = __fadd_rn(__fmul_rn(idx, st.y), st.x);
                sum = fmaf(pq, (float)(1 << (i + 2 * k)), sum);
            }
    float total = __fsub_rn(sum, dterm2[b]);
    float acc = __fdiv_rn(total, 0.9f);
    out[gid] = __fsub_rn(__fdiv_rn(__fmul_rn(2.f, acc), 65025.f), __fdiv_rn(sx2[b], 255.f));
}

extern "C" void kernel_launch(void* const* d_in, const int* in_sizes, int n_in,
                              void* d_out, int out_size, void* d_ws, size_t ws_size,
                              hipStream_t stream)
{
    const float* x      = (const float*)d_in[0];
    const float* w1     = (const float*)d_in[1];
    const float* w3     = (const float*)d_in[2];
    const float* noise1 = (const float*)d_in[3];
    const float* noise3 = (const float*)d_in[4];
    float* out = (float*)d_out;
    float* ws  = (float*)d_ws;

    // ws layout (float offsets)
    float*    xq1    = ws + 0;         // 1024*896
    float*    g1t    = ws + 917504;    // 896*2048
    float*    acc1   = ws + 2752512;   // 1024*512
    float*    xq2    = ws + 3276800;   // 1024*512
    float*    P2     = ws + 3801088;   // 128*10240
    float*    g2t    = ws + 5111808;   // 512*40
    float*    Dq1    = ws + 5132288;   // 56*1024
    float*    Dq2    = ws + 5189632;   // 32*1024
    float*    sx1    = ws + 5222400;   // 1024
    float*    sx2    = ws + 5223424;   // 1024
    float*    dterm1 = ws + 5224448;   // 1024
    float*    dterm2 = ws + 5225472;   // 1024
    float2*   stats2 = (float2*)(ws + 5226496);   // 128 pairs
    unsigned* stats1 = (unsigned*)(ws + 5226752); // 224*2 (pad to 512)
    unsigned* xqb    = (unsigned*)(ws + 5227264); // 8*1024*28 words
    unsigned* xqb2   = (unsigned*)(ws + 5456640); // 8*1024*16 words
    float*    Ps     = ws + 5587712;   // G * 8 * 1024 * 2048

    // s-group size: as many 67MB P s-plane groups as ws allows (>=1 known to fit)
    const size_t fixedf = 5587712;
    const size_t planef = 16777216;  // floats per s (8 i-planes x 1024 x 2048)
    int G = 1;
    while (G < 7 && (fixedf + (size_t)(G + 1) * planef) * sizeof(float) <= ws_size) ++G;

    prep1_kernel<<<1024, 128, 0, stream>>>(x, xq1, sx1, stats1);
    prepg1t_kernel<<<dim3(28, 16), 256, 0, stream>>>(w1, noise1, g1t);
    bitpack_kernel<<<112, 256, 0, stream>>>(xq1, xqb);
    dqpop_kernel<<<56, 256, 0, stream>>>(xqb, Dq1, 7, 28);
    dterm_kernel<<<4, 256, 0, stream>>>(Dq1, dterm1, 7);

    for (int s0 = 0; s0 < 7; s0 += G) {
        int Gc = (7 - s0 < G) ? (7 - s0) : G;
        mm1_kernel<<<dim3(Gc * 64, 16), 256, 0, stream>>>(xqb, g1t, Ps, stats1, s0);
        quant1_kernel<<<512, 256, 0, stream>>>(Ps, stats1, acc1, s0, Gc, s0 == 0);
    }

    finish1_kernel<<<2048, 256, 0, stream>>>(acc1, dterm1, sx1, xq2, xqb2);
    sx2_kernel<<<1024, 128, 0, stream>>>(xq2, sx2);
    prepg2_kernel<<<20, 256, 0, stream>>>(w3, noise3, g2t);
    dqpop_kernel<<<32, 256, 0, stream>>>(xqb2, Dq2, 4, 16);
    dterm_kernel<<<4, 256, 0, stream>>>(Dq2, dterm2, 4);
    mm2_kernel<<<160, 256, 0, stream>>>(xq2, g2t, P2);
    stat2_kernel<<<128, 256, 0, stream>>>(P2, stats2);
    out2_kernel<<<40, 256, 0, stream>>>(P2, stats2, dterm2, sx2, out);
}